// Round 3
// baseline (1017.848 us; speedup 1.0000x reference)
//
#include <hip/hip_runtime.h>

// MultiHeadAttention fwd (B=2,S=2048,D=1024,E=1024,H=16,HD=64) -> (out, attn).
// Round-3 rewrite:
//  - GEMMs: m97 recipe — global_load_lds(16B) staging into linear [128][32] LDS,
//    2-barrier K-loop, 128x128 tile, 4 waves, BK=32.
//  - attn: swapped QK^T (mfma(K,Q)) so each lane owns 4 consecutive k of one q-row:
//    float4 attn stores, ds_write_b64 P staging, per-lane scalar rowsum (reduce = 2 shfl),
//    NO __syncthreads in main loop (lP is wave-private rows), K/V read direct from L2
//    (no LDS staging; per-bh K/V = 256KB, L2-resident). Q pre-scaled by log2e/64 -> exp2.
// Outputs: out fp32 [2,2048,1024] ++ attn fp32 [2,16,2048,2048].

typedef unsigned short u16;
typedef __attribute__((ext_vector_type(8))) short bf16x8;
typedef __attribute__((ext_vector_type(4))) float f32x4;
typedef __attribute__((ext_vector_type(4))) unsigned int u32x4;
typedef __attribute__((ext_vector_type(4))) unsigned short u16x4;

__device__ __forceinline__ u16 f2b(float f) {
  unsigned u = __builtin_bit_cast(unsigned, f);
  unsigned r = u + 0x7FFFu + ((u >> 16) & 1u);   // RNE to bf16
  return (u16)(r >> 16);
}

__device__ __forceinline__ void gload_lds16(const u16* g, u16* l) {
  __builtin_amdgcn_global_load_lds(
      (const __attribute__((address_space(1))) unsigned int*)(const void*)g,
      (__attribute__((address_space(3))) unsigned int*)(void*)l, 16, 0, 0);
}

// ---------------- cast fp32 -> bf16 ----------------
__global__ __launch_bounds__(256) void cast_bf16(const float* __restrict__ in,
                                                 u16* __restrict__ out, int n4) {
  int i = blockIdx.x * 256 + threadIdx.x;
  if (i >= n4) return;
  f32x4 v = ((const f32x4*)in)[i];
  u16x4 o;
  o.x = f2b(v.x); o.y = f2b(v.y); o.z = f2b(v.z); o.w = f2b(v.w);
  ((u16x4*)out)[i] = o;
}

// ---------------- NT bf16 GEMM 128x128, 4 waves (2x2), BK=32, global_load_lds ----------------
// C[m,n] = sum_k A[m,k]*B[n,k] + bias[n].
// EPI==0: fp32 C.  EPI==1: QKV scatter; q is additionally scaled by log2e/64 for exp2 softmax.
template <int EPI>
__global__ __launch_bounds__(256) void gemm_nt(
    const u16* __restrict__ A, const u16* __restrict__ B,
    const float* __restrict__ bias, float* __restrict__ Cout,
    u16* __restrict__ outq, u16* __restrict__ outk, u16* __restrict__ outvT,
    int M, int N, int K) {
  __shared__ u16 lA[128][32];   // linear (no pad): required by global_load_lds
  __shared__ u16 lB[128][32];
  const int t = threadIdx.x;
  const int lane = t & 63;
  const int w = t >> 6;
  const int wr = w >> 1, wc = w & 1;
  const int l15 = lane & 15, lg = lane >> 4;
  const int m0 = blockIdx.y * 128;
  const int n0 = blockIdx.x * 128;
  const int ro = lane >> 2;            // 0..15 row within 16-row chunk
  const int co = (lane & 3) * 8;       // bf16 element 0/8/16/24

  f32x4 acc[4][4] = {};

  for (int k0 = 0; k0 < K; k0 += 32) {
    // wave w stages rows [32w, 32w+32) of both tiles; 2 issues of 1KB each per tile
    const u16* ga = A + (size_t)(m0 + 32 * w + ro) * K + k0 + co;
    const u16* gb = B + (size_t)(n0 + 32 * w + ro) * K + k0 + co;
    gload_lds16(ga,                      &lA[32 * w][0]);
    gload_lds16(ga + (size_t)16 * K,     &lA[32 * w + 16][0]);
    gload_lds16(gb,                      &lB[32 * w][0]);
    gload_lds16(gb + (size_t)16 * K,     &lB[32 * w + 16][0]);
    __syncthreads();
    bf16x8 af[4], bf[4];
#pragma unroll
    for (int i = 0; i < 4; i++)
      af[i] = *(const bf16x8*)&lA[64 * wr + 16 * i + l15][8 * lg];
#pragma unroll
    for (int j = 0; j < 4; j++)
      bf[j] = *(const bf16x8*)&lB[64 * wc + 16 * j + l15][8 * lg];
#pragma unroll
    for (int i = 0; i < 4; i++)
#pragma unroll
      for (int j = 0; j < 4; j++)
        acc[i][j] = __builtin_amdgcn_mfma_f32_16x16x32_bf16(af[i], bf[j], acc[i][j], 0, 0, 0);
    __syncthreads();
  }

  const float QSCALE = 1.442695041f / 64.0f;   // log2(e)/64
  const int r0 = lg * 4;
#pragma unroll
  for (int i = 0; i < 4; i++) {
    const int m = m0 + 64 * wr + 16 * i + r0;
#pragma unroll
    for (int j = 0; j < 4; j++) {
      const int n = n0 + 64 * wc + 16 * j + l15;
      const float bv = bias[n];
      if (EPI == 0) {
#pragma unroll
        for (int r = 0; r < 4; r++)
          Cout[(size_t)(m + r) * N + n] = acc[i][j][r] + bv;
      } else {
        const int h = n / 192;
        const int rem = n - h * 192;       // 16-lane group never straddles 192 (192=12*16)
        const int which = rem >> 6;        // 0=q 1=k 2=v
        const int d = rem & 63;
        const int b = m >> 11;
        const int s = m & 2047;
        const size_t bh = (size_t)b * 16 + h;
        if (which == 0) {
#pragma unroll
          for (int r = 0; r < 4; r++)
            outq[(bh * 2048 + s + r) * 64 + d] = f2b((acc[i][j][r] + bv) * QSCALE);
        } else if (which == 1) {
#pragma unroll
          for (int r = 0; r < 4; r++)
            outk[(bh * 2048 + s + r) * 64 + d] = f2b(acc[i][j][r] + bv);
        } else {
          u16x4 pk;
          pk.x = f2b(acc[i][j][0] + bv); pk.y = f2b(acc[i][j][1] + bv);
          pk.z = f2b(acc[i][j][2] + bv); pk.w = f2b(acc[i][j][3] + bv);
          *(u16x4*)&outvT[(bh * 64 + d) * 2048 + s] = pk;   // s is 4-aligned
        }
      }
    }
  }
}

// ---------------- fused attention (swapped-operand, barrier-free main loop) ----------------
// grid (32 qblocks, 32 bh), 4 waves; wave w owns q-rows qb*64+16w..+15.
// Lane (l15,lg) in j-tile holds scores for q=16w+l15, k=16j+4lg..+3 (consecutive!).
__global__ __launch_bounds__(256) void attn_fused(
    const u16* __restrict__ q, const u16* __restrict__ kk, const u16* __restrict__ vT,
    float* __restrict__ attn, u16* __restrict__ valsb) {
  constexpr int S = 2048, HD = 64;
  __shared__ u16 lP[64][136];    // [q-local][k-local], rows wave-private

  const int t = threadIdx.x;
  const int lane = t & 63;
  const int w = t >> 6;
  const int l15 = lane & 15, lg = lane >> 4;
  const int qb = blockIdx.x;
  const int bh = blockIdx.y;
  const size_t qkbase = (size_t)bh * S * HD;
  const size_t vbase = (size_t)bh * HD * S;
  const int qrow = qb * 64 + 16 * w + l15;

  // Q fragments (q already scaled by log2e/64)
  bf16x8 aq0 = *(const bf16x8*)&q[qkbase + (size_t)qrow * HD + 8 * lg];
  bf16x8 aq1 = *(const bf16x8*)&q[qkbase + (size_t)qrow * HD + 32 + 8 * lg];

  // ---- pass A: row sums of exp2(q'·k) ----
  float rs = 0.f;
  for (int kt = 0; kt < 16; ++kt) {
    const u16* kp = kk + qkbase + (size_t)kt * 128 * HD;
#pragma unroll
    for (int j = 0; j < 8; j++) {
      bf16x8 bk0 = *(const bf16x8*)&kp[(size_t)(16 * j + l15) * HD + 8 * lg];
      bf16x8 bk1 = *(const bf16x8*)&kp[(size_t)(16 * j + l15) * HD + 32 + 8 * lg];
      f32x4 sa = {0.f, 0.f, 0.f, 0.f};
      sa = __builtin_amdgcn_mfma_f32_16x16x32_bf16(bk0, aq0, sa, 0, 0, 0);
      sa = __builtin_amdgcn_mfma_f32_16x16x32_bf16(bk1, aq1, sa, 0, 0, 0);
#pragma unroll
      for (int r = 0; r < 4; r++) rs += __builtin_exp2f(sa[r]);
    }
  }
  rs += __shfl_xor(rs, 16, 64);
  rs += __shfl_xor(rs, 32, 64);
  const float inv = 1.0f / rs;   // per-lane: normalizer for q-row `qrow`

  // ---- pass B: attn float4 stores + P->LDS (b64) + PV ----
  f32x4 vacc[4] = {};
  for (int kt = 0; kt < 16; ++kt) {
    const u16* kp = kk + qkbase + (size_t)kt * 128 * HD;
#pragma unroll
    for (int j = 0; j < 8; j++) {
      bf16x8 bk0 = *(const bf16x8*)&kp[(size_t)(16 * j + l15) * HD + 8 * lg];
      bf16x8 bk1 = *(const bf16x8*)&kp[(size_t)(16 * j + l15) * HD + 32 + 8 * lg];
      f32x4 sa = {0.f, 0.f, 0.f, 0.f};
      sa = __builtin_amdgcn_mfma_f32_16x16x32_bf16(bk0, aq0, sa, 0, 0, 0);
      sa = __builtin_amdgcn_mfma_f32_16x16x32_bf16(bk1, aq1, sa, 0, 0, 0);
      f32x4 pv;
#pragma unroll
      for (int r = 0; r < 4; r++) pv[r] = __builtin_exp2f(sa[r]) * inv;
      *(f32x4*)&attn[((size_t)bh * S + qrow) * S + kt * 128 + 16 * j + 4 * lg] = pv;
      u16x4 pb;
      pb.x = f2b(pv[0]); pb.y = f2b(pv[1]); pb.z = f2b(pv[2]); pb.w = f2b(pv[3]);
      *(u16x4*)&lP[16 * w + l15][16 * j + 4 * lg] = pb;
    }
    // PV: wave reads only its own lP rows (written above by the same wave) — no barrier
#pragma unroll
    for (int s2 = 0; s2 < 4; s2++) {
      bf16x8 pa = *(const bf16x8*)&lP[16 * w + l15][32 * s2 + 8 * lg];
#pragma unroll
      for (int jd = 0; jd < 4; jd++) {
        bf16x8 bv = *(const bf16x8*)&vT[vbase + (size_t)(16 * jd + l15) * S +
                                        kt * 128 + 32 * s2 + 8 * lg];
        vacc[jd] = __builtin_amdgcn_mfma_f32_16x16x32_bf16(pa, bv, vacc[jd], 0, 0, 0);
      }
    }
  }

  // epilogue: vals -> bf16 [(b*2048+s)*1024 + h*64 + d]; lane holds q=16w+4lg+r, d=16jd+l15
  const int b = bh >> 4, h = bh & 15;
#pragma unroll
  for (int jd = 0; jd < 4; jd++) {
    const int d = 16 * jd + l15;
#pragma unroll
    for (int r = 0; r < 4; r++) {
      const int srow = qb * 64 + 16 * w + 4 * lg + r;
      valsb[(size_t)(b * 2048 + srow) * 1024 + h * 64 + d] = f2b(vacc[jd][r]);
    }
  }
}

// ---------------- launch ----------------
extern "C" void kernel_launch(void* const* d_in, const int* in_sizes, int n_in,
                              void* d_out, int out_size, void* d_ws, size_t ws_size,
                              hipStream_t stream) {
  constexpr int B = 2, S = 2048, D = 1024, E = 1024, H = 16;
  constexpr int M = B * S;           // 4096
  const float* x     = (const float*)d_in[0];
  const float* w_qkv = (const float*)d_in[1];
  const float* b_qkv = (const float*)d_in[2];
  const float* w_out = (const float*)d_in[3];
  const float* b_out = (const float*)d_in[4];
  float* out  = (float*)d_out;
  float* attn = out + (size_t)M * D;

  char* ws = (char*)d_ws;
  u16* xb    = (u16*)(ws);                          // 4096*1024 bf16
  u16* wqkvb = (u16*)(ws + 8388608);                // 3072*1024
  u16* woutb = (u16*)(ws + 14680064);               // 1024*1024
  u16* qb    = (u16*)(ws + 16777216);               // [32][2048][64] (pre-scaled)
  u16* kb    = (u16*)(ws + 25165824);               // [32][2048][64]
  u16* vTb   = (u16*)(ws + 33554432);               // [32][64][2048]
  u16* valsb = (u16*)(ws + 41943040);               // 4096*1024

  cast_bf16<<<dim3((M * D / 4 + 255) / 256), 256, 0, stream>>>(x, xb, M * D / 4);
  cast_bf16<<<dim3((3 * E * D / 4 + 255) / 256), 256, 0, stream>>>(w_qkv, wqkvb, 3 * E * D / 4);
  cast_bf16<<<dim3((D * E / 4 + 255) / 256), 256, 0, stream>>>(w_out, woutb, D * E / 4);

  gemm_nt<1><<<dim3(3 * E / 128, M / 128), 256, 0, stream>>>(
      xb, wqkvb, b_qkv, nullptr, qb, kb, vTb, M, 3 * E, D);

  attn_fused<<<dim3(S / 64, B * H), 256, 0, stream>>>(qb, kb, vTb, attn, valsb);

  gemm_nt<0><<<dim3(D / 128, M / 128), 256, 0, stream>>>(
      valsb, woutb, b_out, out, nullptr, nullptr, nullptr, M, D, E);
}